// Round 8
// baseline (1465.513 us; speedup 1.0000x reference)
//
#include <hip/hip_runtime.h>
#include <hip/hip_bf16.h>
#include <math.h>

#define NND 100000   // nodes
#define EE  200000   // edges
#define LL  3        // layers
#define DD  300      // node dim
#define HH  150      // per-direction message dim

#define MPAD 100096  // 782 * 128
#define KP   320     // K padded (multiple of 32)
#define NPJ  640     // proj N padded
#define NUP  384     // update N padded
#define NTK  (KP / 32)

#define NB   49          // scan blocks (2048 elems each)
#define SCN  (NB * 2048) // 100352 >= MPAD+1

#define BSTRIDE 132      // padded fp32 bounce row stride

typedef __attribute__((ext_vector_type(8))) short bf16x8;
typedef __attribute__((ext_vector_type(4))) short bf16x4;
typedef __attribute__((ext_vector_type(4))) float f32x4;

__device__ __forceinline__ float gelu_exact(float z) {
    return 0.5f * z * (1.0f + erff(z * 0.7071067811865475f));
}
__device__ __forceinline__ unsigned short f2bf(float f) {
    union { float fv; unsigned u; } v; v.fv = f;
    unsigned r = v.u + 0x7fff + ((v.u >> 16) & 1);   // RNE (finite inputs)
    return (unsigned short)(r >> 16);
}
__device__ __forceinline__ float bf2f(unsigned short b) {
    union { unsigned u; float fv; } v; v.u = ((unsigned)b) << 16;
    return v.fv;
}

// ---------------- weight packing ----------------
__global__ __launch_bounds__(256) void pack_w(
    const float* __restrict__ Wr, const float* __restrict__ Wc,
    const float* __restrict__ Wa,
    unsigned short* __restrict__ Bt, unsigned short* __restrict__ Wat)
{
    int i = blockIdx.x * 256 + threadIdx.x;
    const int btTotal = LL * NPJ * KP;
    if (i < btTotal) {
        int l = i / (NPJ * KP);
        int rem = i % (NPJ * KP);
        int n = rem / KP;
        int k = rem % KP;
        float v = 0.f;
        if (k < DD && n < 600) {
            const float* W = (n < 300) ? Wr : Wc;
            int nn = (n < 300) ? n : n - 300;
            int krow = (nn < 150) ? k : 300 + k;
            int j    = (nn < 150) ? nn : nn - 150;
            v = W[(size_t)l * 600 * 150 + (size_t)krow * 150 + j];
        }
        Bt[i] = f2bf(v);
    } else {
        int i2 = i - btTotal;
        if (i2 < NUP * KP) {
            int n = i2 / KP, k = i2 % KP;
            float v = (n < DD && k < DD) ? Wa[(size_t)k * DD + n] : 0.f;
            Wat[i2] = f2bf(v);
        }
    }
}

// vbf[MPAD][KP] = bf16(x), zero pads
__global__ __launch_bounds__(256) void init_vbf(
    const float* __restrict__ x, unsigned short* __restrict__ vbf)
{
    int idx = blockIdx.x * 256 + threadIdx.x;       // chunk of 8
    int row = idx / (KP / 8);
    int gk  = (idx % (KP / 8)) * 8;
    if (row >= MPAD) return;
    unsigned short tmp[8];
    if (row < NND && gk < DD) {
        if (gk + 8 <= DD) {
            const float4* p = (const float4*)(x + (size_t)row * DD + gk);
            float4 f0 = p[0], f1 = p[1];
            tmp[0] = f2bf(f0.x); tmp[1] = f2bf(f0.y);
            tmp[2] = f2bf(f0.z); tmp[3] = f2bf(f0.w);
            tmp[4] = f2bf(f1.x); tmp[5] = f2bf(f1.y);
            tmp[6] = f2bf(f1.z); tmp[7] = f2bf(f1.w);
        } else {
            #pragma unroll
            for (int j = 0; j < 8; ++j)
                tmp[j] = (gk + j < DD) ? f2bf(x[(size_t)row * DD + gk + j]) : 0;
        }
    } else {
        #pragma unroll
        for (int j = 0; j < 8; ++j) tmp[j] = 0;
    }
    *((bf16x8*)&vbf[(size_t)row * KP + gk]) = *((bf16x8*)tmp);
}

// ---------------- CSR build ----------------
__global__ __launch_bounds__(256) void hist_deg(
    const int* __restrict__ src, const int* __restrict__ dst,
    int* __restrict__ deg)
{
    int e = blockIdx.x * 256 + threadIdx.x;
    if (e >= EE) return;
    atomicAdd(&deg[dst[e]], 1);
    atomicAdd(&deg[SCN + src[e]], 1);
}

__global__ __launch_bounds__(256) void scanA(
    const int* __restrict__ deg, int* __restrict__ off, int* __restrict__ bsum)
{
    __shared__ int ls[256];
    const int t = threadIdx.x, row = blockIdx.y;
    const int base = blockIdx.x * 2048 + t * 8;
    const int* dg = deg + (size_t)row * SCN + base;
    int v[8];
    #pragma unroll
    for (int j = 0; j < 8; ++j) v[j] = dg[j];
    int tot = 0;
    #pragma unroll
    for (int j = 0; j < 8; ++j) tot += v[j];
    ls[t] = tot;
    __syncthreads();
    #pragma unroll
    for (int d = 1; d < 256; d <<= 1) {
        int tv = (t >= d) ? ls[t - d] : 0;
        __syncthreads();
        ls[t] += tv;
        __syncthreads();
    }
    int run = ls[t] - tot;
    int* op = off + (size_t)row * SCN + base;
    #pragma unroll
    for (int j = 0; j < 8; ++j) { op[j] = run; run += v[j]; }
    if (t == 255) bsum[row * 64 + blockIdx.x] = ls[255];
}

__global__ __launch_bounds__(256) void scanB(int* __restrict__ bsum)
{
    if (threadIdx.x < 2) {
        int row = threadIdx.x, c = 0;
        for (int i = 0; i < NB; ++i) {
            int tv = bsum[row * 64 + i];
            bsum[row * 64 + i] = c;
            c += tv;
        }
    }
}

__global__ __launch_bounds__(256) void scanC(
    int* __restrict__ off, const int* __restrict__ bsum, int* __restrict__ cur)
{
    const int t = threadIdx.x, row = blockIdx.y;
    const int base = blockIdx.x * 2048 + t * 8;
    const int add = bsum[row * 64 + blockIdx.x];
    int* op = off + (size_t)row * SCN + base;
    int* cp = cur + (size_t)row * SCN + base;
    #pragma unroll
    for (int j = 0; j < 8; ++j) {
        int v = op[j] + add;
        op[j] = v;
        cp[j] = v;
    }
}

__global__ __launch_bounds__(256) void fill_adj(
    const int* __restrict__ src, const int* __restrict__ dst,
    int* __restrict__ cur, int* __restrict__ adj)
{
    int e = blockIdx.x * 256 + threadIdx.x;
    if (e >= EE) return;
    int s = src[e], d = dst[e];
    int pd = atomicAdd(&cur[d], 1);
    adj[pd] = s;
    int ps = atomicAdd(&cur[SCN + s], 1);
    adj[EE + ps] = d;
}

// ---------------- aggregation (no atomics) ----------------
__global__ __launch_bounds__(256) void aggregate(
    const int* __restrict__ off, const int* __restrict__ adj,
    const unsigned short* __restrict__ P,
    const float* __restrict__ br, const float* __restrict__ bc,
    unsigned short* __restrict__ RC)
{
    const int n    = blockIdx.x * 4 + (threadIdx.x >> 6);
    const int dir  = blockIdx.y;
    const int lane = threadIdx.x & 63;
    const int h0 = lane, h1 = lane + 64, h2 = lane + 128;

    unsigned short* outrow = RC + (size_t)n * KP + dir * 150;
    if (n >= NND) {
        outrow[h0] = 0; outrow[h1] = 0;
        if (h2 < (dir ? 170 : 150)) outrow[h2] = 0;
        return;
    }

    const int* offp = off + (size_t)dir * SCN;
    const int* adjp = adj + (size_t)dir * EE;
    const float* bias = dir ? bc : br;
    const unsigned short* own = P + (size_t)n * NPJ + dir * 300;
    const int poff = dir ? 450 : 150;

    float o0 = bf2f(own[h0]) + bias[h0];
    float o1 = bf2f(own[h1]) + bias[h1];
    float o2 = (h2 < 150) ? bf2f(own[h2]) + bias[h2] : 0.f;

    float s0 = 0.f, s1 = 0.f, s2 = 0.f;
    int beg = offp[n], end = offp[n + 1];
    for (int i = beg; i < end; ++i) {
        const unsigned short* pp = P + (size_t)adjp[i] * NPJ + poff;
        s0 += gelu_exact(o0 + bf2f(pp[h0]));
        s1 += gelu_exact(o1 + bf2f(pp[h1]));
        if (h2 < 150) s2 += gelu_exact(o2 + bf2f(pp[h2]));
    }
    outrow[h0] = f2bf(s0);
    outrow[h1] = f2bf(s1);
    if (h2 < 150)                  outrow[h2] = f2bf(s2);
    else if (dir == 1 && h2 < 170) outrow[h2] = 0;
}

// ---------------- direct-register MFMA GEMM (no LDS, no barriers in loop) ----
// Block: 256 threads, 4 waves, tile 128x128; wave-tile 64x64 (wr=wid>>1, wc=wid&1).
// Fragments loaded straight from global: lane l reads row (base + l&15),
// k-chunk (l>>4)*8 — 4 lanes cover one 64B line, 16 rows per instruction.
// A streams from HBM (rows disjoint per wr); B panel is L2-resident.
// MODE 0: P[row*NPJ+col] = bf16(acc)
// MODE 1: nv = vbf_old + gelu(acc + bias[col]); last? out=fp32(nv) : vbf=bf16(nv)
template<int MODE>
__global__ __launch_bounds__(256) void gemm_dreg(
    const unsigned short* __restrict__ Ab,
    const unsigned short* __restrict__ Bt,
    unsigned short* __restrict__ P,
    float* __restrict__ outv, unsigned short* __restrict__ vbf,
    const float* __restrict__ bias, int last)
{
    __shared__ float bounce[64 * BSTRIDE];   // ~33.8 KB, epilogue only

    const int tid  = threadIdx.x;
    const int lane = tid & 63;
    const int wid  = tid >> 6;

    // bijective XCD swizzle (m204)
    const int gx   = gridDim.x;
    const int nwg  = gx * gridDim.y;
    const int flat = blockIdx.y * gx + blockIdx.x;
    const int q = nwg >> 3, r = nwg & 7;
    const int xcd = flat & 7, off = flat >> 3;
    const int lid = (xcd < r ? xcd * (q + 1) : r * (q + 1) + (xcd - r) * q) + off;
    const int brow = (lid / gx) * 128;
    const int bcol = (lid % gx) * 128;

    const int wr = wid >> 1;
    const int wc = wid & 1;

    // per-lane fragment base pointers
    const unsigned short* Abase =
        Ab + (size_t)(brow + wr * 64 + (lane & 15)) * KP + (lane >> 4) * 8;
    const unsigned short* Bbase =
        Bt + (size_t)(bcol + wc * 64 + (lane & 15)) * KP + (lane >> 4) * 8;

    f32x4 acc[4][4];
    #pragma unroll
    for (int i = 0; i < 4; ++i)
        #pragma unroll
        for (int j = 0; j < 4; ++j)
            #pragma unroll
            for (int rr = 0; rr < 4; ++rr) acc[i][j][rr] = 0.f;

    #pragma unroll
    for (int t = 0; t < NTK; ++t) {
        bf16x8 af[4], bfr[4];
        #pragma unroll
        for (int mi = 0; mi < 4; ++mi)
            af[mi] = *((const bf16x8*)(Abase + (size_t)mi * 16 * KP + t * 32));
        #pragma unroll
        for (int nj = 0; nj < 4; ++nj)
            bfr[nj] = *((const bf16x8*)(Bbase + (size_t)nj * 16 * KP + t * 32));
        #pragma unroll
        for (int mi = 0; mi < 4; ++mi)
            #pragma unroll
            for (int nj = 0; nj < 4; ++nj)
                acc[mi][nj] = __builtin_amdgcn_mfma_f32_16x16x32_bf16(
                    af[mi], bfr[nj], acc[mi][nj], 0, 0, 0);
    }

    // ---- coalesced epilogue via fp32 LDS bounce (two 64-row halves) ----
    const int ro = tid >> 5;          // 0..7
    const int co = (tid & 31) * 4;    // 0..124
    #pragma unroll
    for (int half = 0; half < 2; ++half) {
        if (wr == half) {
            #pragma unroll
            for (int mi = 0; mi < 4; ++mi)
                #pragma unroll
                for (int nj = 0; nj < 4; ++nj) {
                    int lcol = wc * 64 + nj * 16 + (lane & 15);
                    int rb = mi * 16 + ((lane >> 4) << 2);
                    #pragma unroll
                    for (int rr = 0; rr < 4; ++rr)
                        bounce[(rb + rr) * BSTRIDE + lcol] = acc[mi][nj][rr];
                }
        }
        __syncthreads();
        #pragma unroll
        for (int i = 0; i < 8; ++i) {
            int lrow = ro + i * 8;
            int grow = brow + half * 64 + lrow;
            float4 vv = *(const float4*)&bounce[lrow * BSTRIDE + co];
            if (MODE == 0) {
                bf16x4 o;
                o[0] = (short)f2bf(vv.x); o[1] = (short)f2bf(vv.y);
                o[2] = (short)f2bf(vv.z); o[3] = (short)f2bf(vv.w);
                *((bf16x4*)&P[(size_t)grow * NPJ + bcol + co]) = o;
            } else if (grow < NND) {
                int gc = bcol + co;
                if (bcol < 256) {   // uniform: all 4 cols < 300
                    float4 bv = *(const float4*)&bias[gc];
                    bf16x4 old = *(const bf16x4*)&vbf[(size_t)grow * KP + gc];
                    float4 nv;
                    nv.x = bf2f((unsigned short)old[0]) + gelu_exact(vv.x + bv.x);
                    nv.y = bf2f((unsigned short)old[1]) + gelu_exact(vv.y + bv.y);
                    nv.z = bf2f((unsigned short)old[2]) + gelu_exact(vv.z + bv.z);
                    nv.w = bf2f((unsigned short)old[3]) + gelu_exact(vv.w + bv.w);
                    if (last) {
                        *((float4*)&outv[(size_t)grow * DD + gc]) = nv;
                    } else {
                        bf16x4 o;
                        o[0] = (short)f2bf(nv.x); o[1] = (short)f2bf(nv.y);
                        o[2] = (short)f2bf(nv.z); o[3] = (short)f2bf(nv.w);
                        *((bf16x4*)&vbf[(size_t)grow * KP + gc]) = o;
                    }
                } else {
                    #pragma unroll
                    for (int j = 0; j < 4; ++j) {
                        int c = gc + j;
                        if (c < DD) {
                            float vj = (j == 0) ? vv.x : (j == 1) ? vv.y
                                     : (j == 2) ? vv.z : vv.w;
                            size_t vidx = (size_t)grow * KP + c;
                            float nv = bf2f(vbf[vidx]) + gelu_exact(vj + bias[c]);
                            if (last) outv[(size_t)grow * DD + c] = nv;
                            else      vbf[vidx] = f2bf(nv);
                        }
                    }
                }
            }
        }
        __syncthreads();
    }
}

extern "C" void kernel_launch(void* const* d_in, const int* in_sizes, int n_in,
                              void* d_out, int out_size, void* d_ws, size_t ws_size,
                              hipStream_t stream) {
    const float* x  = (const float*)d_in[0];
    const int*   ei = (const int*)  d_in[1];
    const float* Wr = (const float*)d_in[2];
    const float* br = (const float*)d_in[3];
    const float* Wc = (const float*)d_in[4];
    const float* bc = (const float*)d_in[5];
    const float* Wa = (const float*)d_in[6];
    const float* ba = (const float*)d_in[7];
    float* out = (float*)d_out;

    const size_t P_elems   = (size_t)MPAD * NPJ;   // bf16
    const size_t RC_elems  = (size_t)MPAD * KP;    // bf16
    const size_t V_elems   = (size_t)MPAD * KP;    // bf16
    const size_t Bt_elems  = (size_t)LL * NPJ * KP;
    const size_t Wat_elems = (size_t)NUP * KP;

    unsigned short* P   = (unsigned short*)d_ws;
    unsigned short* RC  = P + P_elems;
    unsigned short* vbf = RC + RC_elems;
    unsigned short* Bt  = vbf + V_elems;
    unsigned short* Wat = Bt + Bt_elems;
    int* deg  = (int*)(Wat + Wat_elems);
    int* off  = deg + 2 * SCN;
    int* curp = off + 2 * SCN;
    int* adj  = curp + 2 * SCN;
    int* bsum = adj + 2 * EE;
    const size_t need = (char*)(bsum + 128) - (char*)d_ws;
    if (ws_size < need) return;  // visible fail (output stays poisoned)

    pack_w<<<2880, 256, 0, stream>>>(Wr, Wc, Wa, Bt, Wat);
    init_vbf<<<(int)((V_elems / 8 + 255) / 256), 256, 0, stream>>>(x, vbf);

    const int* src = ei;
    const int* dst = ei + EE;

    hipMemsetAsync(deg, 0, 2 * SCN * sizeof(int), stream);
    hist_deg<<<(EE + 255) / 256, 256, 0, stream>>>(src, dst, deg);
    scanA<<<dim3(NB, 2), 256, 0, stream>>>(deg, off, bsum);
    scanB<<<1, 256, 0, stream>>>(bsum);
    scanC<<<dim3(NB, 2), 256, 0, stream>>>(off, bsum, curp);
    fill_adj<<<(EE + 255) / 256, 256, 0, stream>>>(src, dst, curp, adj);

    dim3 gproj(NPJ / 128, MPAD / 128);
    dim3 gupd (NUP / 128, MPAD / 128);
    dim3 gagg (MPAD / 4, 2);

    for (int l = 0; l < LL; ++l) {
        gemm_dreg<0><<<gproj, 256, 0, stream>>>(
            vbf, Bt + (size_t)l * NPJ * KP, P, nullptr, nullptr, nullptr, 0);
        aggregate<<<gagg, 256, 0, stream>>>(
            off, adj, P, br + (size_t)l * HH, bc + (size_t)l * HH, RC);
        gemm_dreg<1><<<gupd, 256, 0, stream>>>(
            RC, Wat, nullptr, out, vbf, ba, (l == LL - 1) ? 1 : 0);
    }
}

// Round 9
// 1028.989 us; speedup vs baseline: 1.4242x; 1.4242x over previous
//
#include <hip/hip_runtime.h>
#include <hip/hip_bf16.h>
#include <math.h>

#define NND 100000   // nodes
#define EE  200000   // edges
#define LL  3        // layers
#define DD  300      // node dim
#define HH  150      // per-direction message dim

#define MPAD 100096  // 782 * 128
#define KP   320     // K padded (multiple of 32)
#define NPJ  640     // proj N padded
#define NUP  384     // update N padded
#define NTK  (KP / 32)

#define NB   49          // scan blocks (2048 elems each)
#define SCN  (NB * 2048) // 100352 >= MPAD+1

#define BSTRIDE 132      // padded fp32 bounce row stride (132%32=4 -> 2-way only)

typedef __attribute__((ext_vector_type(8))) short bf16x8;
typedef __attribute__((ext_vector_type(4))) short bf16x4;
typedef __attribute__((ext_vector_type(4))) float f32x4;

__device__ __forceinline__ float gelu_exact(float z) {
    return 0.5f * z * (1.0f + erff(z * 0.7071067811865475f));
}
__device__ __forceinline__ unsigned short f2bf(float f) {
    union { float fv; unsigned u; } v; v.fv = f;
    unsigned r = v.u + 0x7fff + ((v.u >> 16) & 1);   // RNE (finite inputs)
    return (unsigned short)(r >> 16);
}
__device__ __forceinline__ float bf2f(unsigned short b) {
    union { unsigned u; float fv; } v; v.u = ((unsigned)b) << 16;
    return v.fv;
}

// ---------------- weight packing ----------------
__global__ __launch_bounds__(256) void pack_w(
    const float* __restrict__ Wr, const float* __restrict__ Wc,
    const float* __restrict__ Wa,
    unsigned short* __restrict__ Bt, unsigned short* __restrict__ Wat)
{
    int i = blockIdx.x * 256 + threadIdx.x;
    const int btTotal = LL * NPJ * KP;
    if (i < btTotal) {
        int l = i / (NPJ * KP);
        int rem = i % (NPJ * KP);
        int n = rem / KP;
        int k = rem % KP;
        float v = 0.f;
        if (k < DD && n < 600) {
            const float* W = (n < 300) ? Wr : Wc;
            int nn = (n < 300) ? n : n - 300;
            int krow = (nn < 150) ? k : 300 + k;
            int j    = (nn < 150) ? nn : nn - 150;
            v = W[(size_t)l * 600 * 150 + (size_t)krow * 150 + j];
        }
        Bt[i] = f2bf(v);
    } else {
        int i2 = i - btTotal;
        if (i2 < NUP * KP) {
            int n = i2 / KP, k = i2 % KP;
            float v = (n < DD && k < DD) ? Wa[(size_t)k * DD + n] : 0.f;
            Wat[i2] = f2bf(v);
        }
    }
}

// vbf[MPAD][KP] = bf16(x), zero pads
__global__ __launch_bounds__(256) void init_vbf(
    const float* __restrict__ x, unsigned short* __restrict__ vbf)
{
    int idx = blockIdx.x * 256 + threadIdx.x;       // chunk of 8
    int row = idx / (KP / 8);
    int gk  = (idx % (KP / 8)) * 8;
    if (row >= MPAD) return;
    unsigned short tmp[8];
    if (row < NND && gk < DD) {
        if (gk + 8 <= DD) {
            const float4* p = (const float4*)(x + (size_t)row * DD + gk);
            float4 f0 = p[0], f1 = p[1];
            tmp[0] = f2bf(f0.x); tmp[1] = f2bf(f0.y);
            tmp[2] = f2bf(f0.z); tmp[3] = f2bf(f0.w);
            tmp[4] = f2bf(f1.x); tmp[5] = f2bf(f1.y);
            tmp[6] = f2bf(f1.z); tmp[7] = f2bf(f1.w);
        } else {
            #pragma unroll
            for (int j = 0; j < 8; ++j)
                tmp[j] = (gk + j < DD) ? f2bf(x[(size_t)row * DD + gk + j]) : 0;
        }
    } else {
        #pragma unroll
        for (int j = 0; j < 8; ++j) tmp[j] = 0;
    }
    *((bf16x8*)&vbf[(size_t)row * KP + gk]) = *((bf16x8*)tmp);
}

// ---------------- CSR build ----------------
__global__ __launch_bounds__(256) void hist_deg(
    const int* __restrict__ src, const int* __restrict__ dst,
    int* __restrict__ deg)
{
    int e = blockIdx.x * 256 + threadIdx.x;
    if (e >= EE) return;
    atomicAdd(&deg[dst[e]], 1);
    atomicAdd(&deg[SCN + src[e]], 1);
}

__global__ __launch_bounds__(256) void scanA(
    const int* __restrict__ deg, int* __restrict__ off, int* __restrict__ bsum)
{
    __shared__ int ls[256];
    const int t = threadIdx.x, row = blockIdx.y;
    const int base = blockIdx.x * 2048 + t * 8;
    const int* dg = deg + (size_t)row * SCN + base;
    int v[8];
    #pragma unroll
    for (int j = 0; j < 8; ++j) v[j] = dg[j];
    int tot = 0;
    #pragma unroll
    for (int j = 0; j < 8; ++j) tot += v[j];
    ls[t] = tot;
    __syncthreads();
    #pragma unroll
    for (int d = 1; d < 256; d <<= 1) {
        int tv = (t >= d) ? ls[t - d] : 0;
        __syncthreads();
        ls[t] += tv;
        __syncthreads();
    }
    int run = ls[t] - tot;
    int* op = off + (size_t)row * SCN + base;
    #pragma unroll
    for (int j = 0; j < 8; ++j) { op[j] = run; run += v[j]; }
    if (t == 255) bsum[row * 64 + blockIdx.x] = ls[255];
}

__global__ __launch_bounds__(256) void scanB(int* __restrict__ bsum)
{
    if (threadIdx.x < 2) {
        int row = threadIdx.x, c = 0;
        for (int i = 0; i < NB; ++i) {
            int tv = bsum[row * 64 + i];
            bsum[row * 64 + i] = c;
            c += tv;
        }
    }
}

__global__ __launch_bounds__(256) void scanC(
    int* __restrict__ off, const int* __restrict__ bsum, int* __restrict__ cur)
{
    const int t = threadIdx.x, row = blockIdx.y;
    const int base = blockIdx.x * 2048 + t * 8;
    const int add = bsum[row * 64 + blockIdx.x];
    int* op = off + (size_t)row * SCN + base;
    int* cp = cur + (size_t)row * SCN + base;
    #pragma unroll
    for (int j = 0; j < 8; ++j) {
        int v = op[j] + add;
        op[j] = v;
        cp[j] = v;
    }
}

__global__ __launch_bounds__(256) void fill_adj(
    const int* __restrict__ src, const int* __restrict__ dst,
    int* __restrict__ cur, int* __restrict__ adj)
{
    int e = blockIdx.x * 256 + threadIdx.x;
    if (e >= EE) return;
    int s = src[e], d = dst[e];
    int pd = atomicAdd(&cur[d], 1);
    adj[pd] = s;
    int ps = atomicAdd(&cur[SCN + s], 1);
    adj[EE + ps] = d;
}

// ---------------- aggregation (no atomics) ----------------
__global__ __launch_bounds__(256) void aggregate(
    const int* __restrict__ off, const int* __restrict__ adj,
    const unsigned short* __restrict__ P,
    const float* __restrict__ br, const float* __restrict__ bc,
    unsigned short* __restrict__ RC)
{
    const int n    = blockIdx.x * 4 + (threadIdx.x >> 6);
    const int dir  = blockIdx.y;
    const int lane = threadIdx.x & 63;
    const int h0 = lane, h1 = lane + 64, h2 = lane + 128;

    unsigned short* outrow = RC + (size_t)n * KP + dir * 150;
    if (n >= NND) {
        outrow[h0] = 0; outrow[h1] = 0;
        if (h2 < (dir ? 170 : 150)) outrow[h2] = 0;
        return;
    }

    const int* offp = off + (size_t)dir * SCN;
    const int* adjp = adj + (size_t)dir * EE;
    const float* bias = dir ? bc : br;
    const unsigned short* own = P + (size_t)n * NPJ + dir * 300;
    const int poff = dir ? 450 : 150;

    float o0 = bf2f(own[h0]) + bias[h0];
    float o1 = bf2f(own[h1]) + bias[h1];
    float o2 = (h2 < 150) ? bf2f(own[h2]) + bias[h2] : 0.f;

    float s0 = 0.f, s1 = 0.f, s2 = 0.f;
    int beg = offp[n], end = offp[n + 1];
    for (int i = beg; i < end; ++i) {
        const unsigned short* pp = P + (size_t)adjp[i] * NPJ + poff;
        s0 += gelu_exact(o0 + bf2f(pp[h0]));
        s1 += gelu_exact(o1 + bf2f(pp[h1]));
        if (h2 < 150) s2 += gelu_exact(o2 + bf2f(pp[h2]));
    }
    outrow[h0] = f2bf(s0);
    outrow[h1] = f2bf(s1);
    if (h2 < 150)                  outrow[h2] = f2bf(s2);
    else if (dir == 1 && h2 < 170) outrow[h2] = 0;
}

// ---------------- MFMA GEMM: 128x128, 4-buffer, 1 barrier/K-step ----------------
#define GLOAD16(gp, lp) __builtin_amdgcn_global_load_lds( \
    (const __attribute__((address_space(1))) unsigned int*)(gp), \
    (__attribute__((address_space(3))) unsigned int*)(lp), 16, 0, 0)

#define STAGE_LDS(dstp, srcbase, rowoff, k0) do {                            \
    _Pragma("unroll")                                                        \
    for (int i_ = 0; i_ < 2; ++i_) {                                         \
        int cb_ = wid * 128 + i_ * 64;                                       \
        int ci_ = cb_ + lane;                                                \
        int row_ = ci_ >> 2, pc_ = ci_ & 3;                                  \
        int c_ = pc_ ^ ((row_ >> 1) & 3);                                    \
        GLOAD16(srcbase + (size_t)(rowoff + row_) * KP + (k0) + c_ * 8,      \
                &(dstp)[cb_ * 8]);                                           \
    } } while (0)

// C[128x128 tiles] = A[M,KP](bf16) @ Bt[N,KP]^T(bf16)
// MODE 0: P[row*NPJ+col] = bf16(acc)
// MODE 1: nv = vbf_old + gelu(acc + bias[col]); last? out=fp32(nv) : vbf=bf16(nv)
template<int MODE>
__global__ __launch_bounds__(256) void gemm_mfma(
    const unsigned short* __restrict__ Ab,
    const unsigned short* __restrict__ Bt,
    unsigned short* __restrict__ P,
    float* __restrict__ outv, unsigned short* __restrict__ vbf,
    const float* __restrict__ bias, int last)
{
    __shared__ char smem[4 * 16384];   // 64 KB: 4 x (A 8KB + B 8KB)
    float* bounce = (float*)smem;      // 64 x BSTRIDE fp32 (33.8KB), epilogue only

    const int tid  = threadIdx.x;
    const int lane = tid & 63;
    const int wid  = tid >> 6;

    // bijective XCD swizzle (m204)
    const int gx   = gridDim.x;
    const int nwg  = gx * gridDim.y;
    const int flat = blockIdx.y * gx + blockIdx.x;
    const int q = nwg >> 3, r = nwg & 7;
    const int xcd = flat & 7, off = flat >> 3;
    const int lid = (xcd < r ? xcd * (q + 1) : r * (q + 1) + (xcd - r) * q) + off;
    const int brow = (lid / gx) * 128;
    const int bcol = (lid % gx) * 128;

    const int wm = (wid >> 1) * 64;
    const int wn = (wid & 1) * 64;

    f32x4 acc[4][4];
    #pragma unroll
    for (int i = 0; i < 4; ++i)
        #pragma unroll
        for (int j = 0; j < 4; ++j)
            #pragma unroll
            for (int rr = 0; rr < 4; ++rr) acc[i][j][rr] = 0.f;

    // prologue: stage tiles 0,1 into bufs 0,1 (4 vmem ops per wave per tile)
    #pragma unroll
    for (int t = 0; t < 2; ++t) {
        unsigned short* Al = (unsigned short*)(smem + t * 16384);
        unsigned short* Bl = (unsigned short*)(smem + t * 16384 + 8192);
        STAGE_LDS(Al, Ab, brow, t * 32);
        STAGE_LDS(Bl, Bt, bcol, t * 32);
    }

    #pragma unroll
    for (int t = 0; t < NTK; ++t) {
        const int b = t & 3;
        unsigned short* Alc = (unsigned short*)(smem + b * 16384);
        unsigned short* Blc = (unsigned short*)(smem + b * 16384 + 8192);
        if (t + 2 < NTK) {
            const int bn = (t + 2) & 3;
            unsigned short* Aln = (unsigned short*)(smem + bn * 16384);
            unsigned short* Bln = (unsigned short*)(smem + bn * 16384 + 8192);
            STAGE_LDS(Aln, Ab, brow, (t + 2) * 32);
            STAGE_LDS(Bln, Bt, bcol, (t + 2) * 32);
            // own tile-t loads done; tiles t+1,t+2 (8 loads) stay in flight
            asm volatile("s_waitcnt vmcnt(8)" ::: "memory");
        } else if (t + 1 < NTK) {
            asm volatile("s_waitcnt vmcnt(4)" ::: "memory");
        } else {
            asm volatile("s_waitcnt vmcnt(0)" ::: "memory");
        }
        __builtin_amdgcn_s_barrier();   // all waves' tile-t data landed

        bf16x8 af[4], bfr[4];
        #pragma unroll
        for (int mi = 0; mi < 4; ++mi) {
            int row = wm + mi * 16 + (lane & 15);
            af[mi] = *((const bf16x8*)&Alc[row * 32 + (((lane >> 4) ^ ((row >> 1) & 3)) * 8)]);
        }
        #pragma unroll
        for (int nj = 0; nj < 4; ++nj) {
            int row = wn + nj * 16 + (lane & 15);
            bfr[nj] = *((const bf16x8*)&Blc[row * 32 + (((lane >> 4) ^ ((row >> 1) & 3)) * 8)]);
        }
        __builtin_amdgcn_s_setprio(1);
        #pragma unroll
        for (int mi = 0; mi < 4; ++mi)
            #pragma unroll
            for (int nj = 0; nj < 4; ++nj)
                acc[mi][nj] = __builtin_amdgcn_mfma_f32_16x16x32_bf16(
                    af[mi], bfr[nj], acc[mi][nj], 0, 0, 0);
        __builtin_amdgcn_s_setprio(0);
        // NO second barrier: 4 buffers keep re-stage target >=3 steps from readers
    }
    __builtin_amdgcn_s_barrier();   // protect smem before bounce reuse

    // ---- coalesced epilogue via fp32 LDS bounce (two 64-row halves) ----
    const int ro = tid >> 5;          // 0..7
    const int co = (tid & 31) * 4;    // 0..124
    #pragma unroll
    for (int half = 0; half < 2; ++half) {
        if (wm == half * 64) {
            #pragma unroll
            for (int mi = 0; mi < 4; ++mi)
                #pragma unroll
                for (int nj = 0; nj < 4; ++nj) {
                    int lcol = wn + nj * 16 + (lane & 15);
                    int rb = mi * 16 + ((lane >> 4) << 2);
                    #pragma unroll
                    for (int rr = 0; rr < 4; ++rr)
                        bounce[(rb + rr) * BSTRIDE + lcol] = acc[mi][nj][rr];
                }
        }
        __syncthreads();
        #pragma unroll
        for (int i = 0; i < 8; ++i) {
            int lrow = ro + i * 8;
            int grow = brow + half * 64 + lrow;
            float4 vv = *(const float4*)&bounce[lrow * BSTRIDE + co];
            if (MODE == 0) {
                bf16x4 o;
                o[0] = (short)f2bf(vv.x); o[1] = (short)f2bf(vv.y);
                o[2] = (short)f2bf(vv.z); o[3] = (short)f2bf(vv.w);
                *((bf16x4*)&P[(size_t)grow * NPJ + bcol + co]) = o;
            } else if (grow < NND) {
                int gc = bcol + co;
                if (bcol < 256) {   // uniform: all 4 cols < 300
                    float4 bv = *(const float4*)&bias[gc];
                    bf16x4 old = *(const bf16x4*)&vbf[(size_t)grow * KP + gc];
                    float4 nv;
                    nv.x = bf2f((unsigned short)old[0]) + gelu_exact(vv.x + bv.x);
                    nv.y = bf2f((unsigned short)old[1]) + gelu_exact(vv.y + bv.y);
                    nv.z = bf2f((unsigned short)old[2]) + gelu_exact(vv.z + bv.z);
                    nv.w = bf2f((unsigned short)old[3]) + gelu_exact(vv.w + bv.w);
                    if (last) {
                        *((float4*)&outv[(size_t)grow * DD + gc]) = nv;
                    } else {
                        bf16x4 o;
                        o[0] = (short)f2bf(nv.x); o[1] = (short)f2bf(nv.y);
                        o[2] = (short)f2bf(nv.z); o[3] = (short)f2bf(nv.w);
                        *((bf16x4*)&vbf[(size_t)grow * KP + gc]) = o;
                    }
                } else {
                    #pragma unroll
                    for (int j = 0; j < 4; ++j) {
                        int c = gc + j;
                        if (c < DD) {
                            float vj = (j == 0) ? vv.x : (j == 1) ? vv.y
                                     : (j == 2) ? vv.z : vv.w;
                            size_t vidx = (size_t)grow * KP + c;
                            float nv = bf2f(vbf[vidx]) + gelu_exact(vj + bias[c]);
                            if (last) outv[(size_t)grow * DD + c] = nv;
                            else      vbf[vidx] = f2bf(nv);
                        }
                    }
                }
            }
        }
        __syncthreads();
    }
}

extern "C" void kernel_launch(void* const* d_in, const int* in_sizes, int n_in,
                              void* d_out, int out_size, void* d_ws, size_t ws_size,
                              hipStream_t stream) {
    const float* x  = (const float*)d_in[0];
    const int*   ei = (const int*)  d_in[1];
    const float* Wr = (const float*)d_in[2];
    const float* br = (const float*)d_in[3];
    const float* Wc = (const float*)d_in[4];
    const float* bc = (const float*)d_in[5];
    const float* Wa = (const float*)d_in[6];
    const float* ba = (const float*)d_in[7];
    float* out = (float*)d_out;

    const size_t P_elems   = (size_t)MPAD * NPJ;   // bf16
    const size_t RC_elems  = (size_t)MPAD * KP;    // bf16
    const size_t V_elems   = (size_t)MPAD * KP;    // bf16
    const size_t Bt_elems  = (size_t)LL * NPJ * KP;
    const size_t Wat_elems = (size_t)NUP * KP;

    unsigned short* P   = (unsigned short*)d_ws;
    unsigned short* RC  = P + P_elems;
    unsigned short* vbf = RC + RC_elems;
    unsigned short* Bt  = vbf + V_elems;
    unsigned short* Wat = Bt + Bt_elems;
    int* deg  = (int*)(Wat + Wat_elems);
    int* off  = deg + 2 * SCN;
    int* curp = off + 2 * SCN;
    int* adj  = curp + 2 * SCN;
    int* bsum = adj + 2 * EE;
    const size_t need = (char*)(bsum + 128) - (char*)d_ws;
    if (ws_size < need) return;  // visible fail (output stays poisoned)

    pack_w<<<2880, 256, 0, stream>>>(Wr, Wc, Wa, Bt, Wat);
    init_vbf<<<(int)((V_elems / 8 + 255) / 256), 256, 0, stream>>>(x, vbf);

    const int* src = ei;
    const int* dst = ei + EE;

    hipMemsetAsync(deg, 0, 2 * SCN * sizeof(int), stream);
    hist_deg<<<(EE + 255) / 256, 256, 0, stream>>>(src, dst, deg);
    scanA<<<dim3(NB, 2), 256, 0, stream>>>(deg, off, bsum);
    scanB<<<1, 256, 0, stream>>>(bsum);
    scanC<<<dim3(NB, 2), 256, 0, stream>>>(off, bsum, curp);
    fill_adj<<<(EE + 255) / 256, 256, 0, stream>>>(src, dst, curp, adj);

    dim3 gproj(NPJ / 128, MPAD / 128);
    dim3 gupd (NUP / 128, MPAD / 128);
    dim3 gagg (MPAD / 4, 2);

    for (int l = 0; l < LL; ++l) {
        gemm_mfma<0><<<gproj, 256, 0, stream>>>(
            vbf, Bt + (size_t)l * NPJ * KP, P, nullptr, nullptr, nullptr, 0);
        aggregate<<<gagg, 256, 0, stream>>>(
            off, adj, P, br + (size_t)l * HH, bc + (size_t)l * HH, RC);
        gemm_mfma<1><<<gupd, 256, 0, stream>>>(
            RC, Wat, nullptr, out, vbf, ba, (l == LL - 1) ? 1 : 0);
    }
}

// Round 10
// 954.919 us; speedup vs baseline: 1.5347x; 1.0776x over previous
//
#include <hip/hip_runtime.h>
#include <hip/hip_bf16.h>
#include <math.h>

#define NND 100000   // nodes
#define EE  200000   // edges
#define LL  3        // layers
#define DD  300      // node dim
#define HH  150      // per-direction message dim

#define MPAD 100096  // 782 * 128
#define KP   320     // K padded (multiple of 32)
#define NPJ  640     // proj N padded
#define NUP  384     // update N padded
#define NTK  (KP / 32)

#define NB   49          // scan blocks (2048 elems each)
#define SCN  (NB * 2048) // 100352 >= MPAD+1

#define BSTRIDE 132      // padded fp32 bounce row stride

// P column layout (all 8B-aligned region starts, pads zero):
//  Br @   0..149   (r-dir neighbor part, gathered)
//  Bc @ 152..301   (c-dir neighbor part, gathered)
//  Ar @ 304..453   (r-dir own part)
//  Ac @ 456..605   (c-dir own part)
#define P_BR 0
#define P_BC 152
#define P_AR 304
#define P_AC 456
// RC column layout: r @ 0..149, pad 150..159, c @ 160..309, pad 310..319
#define RC_R 0
#define RC_C 160

typedef __attribute__((ext_vector_type(8))) short bf16x8;
typedef __attribute__((ext_vector_type(4))) short bf16x4;
typedef __attribute__((ext_vector_type(4))) float f32x4;

__device__ __forceinline__ float gelu_exact(float z) {
    return 0.5f * z * (1.0f + erff(z * 0.7071067811865475f));
}
__device__ __forceinline__ unsigned short f2bf(float f) {
    union { float fv; unsigned u; } v; v.fv = f;
    unsigned r = v.u + 0x7fff + ((v.u >> 16) & 1);   // RNE (finite inputs)
    return (unsigned short)(r >> 16);
}
__device__ __forceinline__ float bf2f(unsigned short b) {
    union { unsigned u; float fv; } v; v.u = ((unsigned)b) << 16;
    return v.fv;
}

// ---------------- weight packing ----------------
// Bt[l][n][k]: col n per P layout above; Wat[n][k]: k per RC layout
__global__ __launch_bounds__(256) void pack_w(
    const float* __restrict__ Wr, const float* __restrict__ Wc,
    const float* __restrict__ Wa,
    unsigned short* __restrict__ Bt, unsigned short* __restrict__ Wat)
{
    int i = blockIdx.x * 256 + threadIdx.x;
    const int btTotal = LL * NPJ * KP;
    if (i < btTotal) {
        int l = i / (NPJ * KP);
        int rem = i % (NPJ * KP);
        int n = rem / KP;
        int k = rem % KP;
        float v = 0.f;
        if (k < DD) {
            const float* W = nullptr; int krow = k, j = -1;
            if (n >= P_BR && n < P_BR + 150)      { W = Wr; krow = 300 + k; j = n - P_BR; }
            else if (n >= P_BC && n < P_BC + 150) { W = Wc; krow = 300 + k; j = n - P_BC; }
            else if (n >= P_AR && n < P_AR + 150) { W = Wr; krow = k;       j = n - P_AR; }
            else if (n >= P_AC && n < P_AC + 150) { W = Wc; krow = k;       j = n - P_AC; }
            if (j >= 0)
                v = W[(size_t)l * 600 * 150 + (size_t)krow * 150 + j];
        }
        Bt[i] = f2bf(v);
    } else {
        int i2 = i - btTotal;
        if (i2 < NUP * KP) {
            int n = i2 / KP, k = i2 % KP;
            int kk = -1;
            if (k < 150)                 kk = k;          // r rows of Wa
            else if (k >= 160 && k < 310) kk = k - 10;    // c rows of Wa
            float v = (n < DD && kk >= 0) ? Wa[(size_t)kk * DD + n] : 0.f;
            Wat[i2] = f2bf(v);
        }
    }
}

// vbf[MPAD][KP] = bf16(x), zero pads
__global__ __launch_bounds__(256) void init_vbf(
    const float* __restrict__ x, unsigned short* __restrict__ vbf)
{
    int idx = blockIdx.x * 256 + threadIdx.x;       // chunk of 8
    int row = idx / (KP / 8);
    int gk  = (idx % (KP / 8)) * 8;
    if (row >= MPAD) return;
    unsigned short tmp[8];
    if (row < NND && gk < DD) {
        if (gk + 8 <= DD) {
            const float4* p = (const float4*)(x + (size_t)row * DD + gk);
            float4 f0 = p[0], f1 = p[1];
            tmp[0] = f2bf(f0.x); tmp[1] = f2bf(f0.y);
            tmp[2] = f2bf(f0.z); tmp[3] = f2bf(f0.w);
            tmp[4] = f2bf(f1.x); tmp[5] = f2bf(f1.y);
            tmp[6] = f2bf(f1.z); tmp[7] = f2bf(f1.w);
        } else {
            #pragma unroll
            for (int j = 0; j < 8; ++j)
                tmp[j] = (gk + j < DD) ? f2bf(x[(size_t)row * DD + gk + j]) : 0;
        }
    } else {
        #pragma unroll
        for (int j = 0; j < 8; ++j) tmp[j] = 0;
    }
    *((bf16x8*)&vbf[(size_t)row * KP + gk]) = *((bf16x8*)tmp);
}

// ---------------- CSR build ----------------
__global__ __launch_bounds__(256) void hist_deg(
    const int* __restrict__ src, const int* __restrict__ dst,
    int* __restrict__ deg)
{
    int e = blockIdx.x * 256 + threadIdx.x;
    if (e >= EE) return;
    atomicAdd(&deg[dst[e]], 1);
    atomicAdd(&deg[SCN + src[e]], 1);
}

__global__ __launch_bounds__(256) void scanA(
    const int* __restrict__ deg, int* __restrict__ off, int* __restrict__ bsum)
{
    __shared__ int ls[256];
    const int t = threadIdx.x, row = blockIdx.y;
    const int base = blockIdx.x * 2048 + t * 8;
    const int* dg = deg + (size_t)row * SCN + base;
    int v[8];
    #pragma unroll
    for (int j = 0; j < 8; ++j) v[j] = dg[j];
    int tot = 0;
    #pragma unroll
    for (int j = 0; j < 8; ++j) tot += v[j];
    ls[t] = tot;
    __syncthreads();
    #pragma unroll
    for (int d = 1; d < 256; d <<= 1) {
        int tv = (t >= d) ? ls[t - d] : 0;
        __syncthreads();
        ls[t] += tv;
        __syncthreads();
    }
    int run = ls[t] - tot;
    int* op = off + (size_t)row * SCN + base;
    #pragma unroll
    for (int j = 0; j < 8; ++j) { op[j] = run; run += v[j]; }
    if (t == 255) bsum[row * 64 + blockIdx.x] = ls[255];
}

__global__ __launch_bounds__(256) void scanB(int* __restrict__ bsum)
{
    if (threadIdx.x < 2) {
        int row = threadIdx.x, c = 0;
        for (int i = 0; i < NB; ++i) {
            int tv = bsum[row * 64 + i];
            bsum[row * 64 + i] = c;
            c += tv;
        }
    }
}

__global__ __launch_bounds__(256) void scanC(
    int* __restrict__ off, const int* __restrict__ bsum, int* __restrict__ cur)
{
    const int t = threadIdx.x, row = blockIdx.y;
    const int base = blockIdx.x * 2048 + t * 8;
    const int add = bsum[row * 64 + blockIdx.x];
    int* op = off + (size_t)row * SCN + base;
    int* cp = cur + (size_t)row * SCN + base;
    #pragma unroll
    for (int j = 0; j < 8; ++j) {
        int v = op[j] + add;
        op[j] = v;
        cp[j] = v;
    }
}

__global__ __launch_bounds__(256) void fill_adj(
    const int* __restrict__ src, const int* __restrict__ dst,
    int* __restrict__ cur, int* __restrict__ adj)
{
    int e = blockIdx.x * 256 + threadIdx.x;
    if (e >= EE) return;
    int s = src[e], d = dst[e];
    int pd = atomicAdd(&cur[d], 1);
    adj[pd] = s;
    int ps = atomicAdd(&cur[SCN + s], 1);
    adj[EE + ps] = d;
}

// ---------------- aggregation (no atomics, vectorized aligned gathers) ------
// dir 0 (r at n, in-edges):  sum gelu( Ar[n] + Br[s] + br ) -> RC[n][RC_R..]
// dir 1 (c at n, out-edges): sum gelu( Ac[n] + Bc[d] + bc ) -> RC[n][RC_C..]
__global__ __launch_bounds__(256) void aggregate(
    const int* __restrict__ off, const int* __restrict__ adj,
    const unsigned short* __restrict__ P,
    const float* __restrict__ br, const float* __restrict__ bc,
    unsigned short* __restrict__ RC)
{
    const int n    = blockIdx.x * 4 + (threadIdx.x >> 6);
    const int dir  = blockIdx.y;
    const int lane = threadIdx.x & 63;
    const int c    = lane * 4;             // col base within 150-wide region

    // zero the K-pad columns (dir0 owns 150..159, dir1 owns 310..319)
    if (lane < 10)
        RC[(size_t)n * KP + (dir ? 310 : 150) + lane] = 0;
    if (c >= 152) return;                  // lanes 38..63 done

    const int* offp = off + (size_t)dir * SCN;
    const int* adjp = adj + (size_t)dir * EE;
    const float* bias = dir ? bc : br;
    const unsigned short* own = P + (size_t)n * NPJ + (dir ? P_AC : P_AR);
    const int poff = dir ? P_BC : P_BR;

    const bool g0 = (c + 0) < 150, g1 = (c + 1) < 150;
    const bool g2 = (c + 2) < 150, g3 = (c + 3) < 150;

    bf16x4 ow = *((const bf16x4*)&own[c]);   // 8B-aligned; over-read lands in pads
    float o0 = bf2f((unsigned short)ow[0]) + (g0 ? bias[c + 0] : 0.f);
    float o1 = bf2f((unsigned short)ow[1]) + (g1 ? bias[c + 1] : 0.f);
    float o2 = bf2f((unsigned short)ow[2]) + (g2 ? bias[c + 2] : 0.f);
    float o3 = bf2f((unsigned short)ow[3]) + (g3 ? bias[c + 3] : 0.f);

    float s0 = 0.f, s1 = 0.f, s2 = 0.f, s3 = 0.f;
    int beg = offp[n], end = offp[n + 1];
    if (beg < end) {
        int a = adjp[beg];
        for (int i = beg; i < end; ++i) {
            int anext = (i + 1 < end) ? adjp[i + 1] : 0;   // prefetch index
            const unsigned short* pp = P + (size_t)a * NPJ + poff;
            bf16x4 pv = *((const bf16x4*)&pp[c]);          // ONE aligned 8B load
            s0 += gelu_exact(o0 + bf2f((unsigned short)pv[0]));
            s1 += gelu_exact(o1 + bf2f((unsigned short)pv[1]));
            s2 += gelu_exact(o2 + bf2f((unsigned short)pv[2]));
            s3 += gelu_exact(o3 + bf2f((unsigned short)pv[3]));
            a = anext;
        }
    }
    unsigned short* outrow = RC + (size_t)n * KP + (dir ? RC_C : RC_R);
    if (c + 4 <= 150) {
        bf16x4 o;
        o[0] = (short)f2bf(s0); o[1] = (short)f2bf(s1);
        o[2] = (short)f2bf(s2); o[3] = (short)f2bf(s3);
        *((bf16x4*)&outrow[c]) = o;        // base ≡ 0 mod 4 elems -> 8B aligned
    } else {                                // lane 37: cols 148,149 only
        if (g0) outrow[c + 0] = f2bf(s0);
        if (g1) outrow[c + 1] = f2bf(s1);
    }
}

// ---------------- MFMA GEMM: 128x128, 4-buffer, depth-3, 1 barrier/K-step ----
#define GLOAD16(gp, lp) __builtin_amdgcn_global_load_lds( \
    (const __attribute__((address_space(1))) unsigned int*)(gp), \
    (__attribute__((address_space(3))) unsigned int*)(lp), 16, 0, 0)

#define STAGE_LDS(dstp, srcbase, rowoff, k0) do {                            \
    _Pragma("unroll")                                                        \
    for (int i_ = 0; i_ < 2; ++i_) {                                         \
        int cb_ = wid * 128 + i_ * 64;                                       \
        int ci_ = cb_ + lane;                                                \
        int row_ = ci_ >> 2, pc_ = ci_ & 3;                                  \
        int c_ = pc_ ^ ((row_ >> 1) & 3);                                    \
        GLOAD16(srcbase + (size_t)(rowoff + row_) * KP + (k0) + c_ * 8,      \
                &(dstp)[cb_ * 8]);                                           \
    } } while (0)

// C[128x128 tiles] = A[M,KP](bf16) @ Bt[N,KP]^T(bf16)
// MODE 0: P[row*NPJ+col] = bf16(acc)
// MODE 1: nv = vbf_old + gelu(acc + bias[col]); last? out=fp32(nv) : vbf=bf16(nv)
template<int MODE>
__global__ __launch_bounds__(256) void gemm_mfma(
    const unsigned short* __restrict__ Ab,
    const unsigned short* __restrict__ Bt,
    unsigned short* __restrict__ P,
    float* __restrict__ outv, unsigned short* __restrict__ vbf,
    const float* __restrict__ bias, int last)
{
    __shared__ char smem[4 * 16384];   // 64 KB: 4 x (A 8KB + B 8KB)
    float* bounce = (float*)smem;      // 64 x BSTRIDE fp32, epilogue only

    const int tid  = threadIdx.x;
    const int lane = tid & 63;
    const int wid  = tid >> 6;

    // bijective XCD swizzle (m204)
    const int gx   = gridDim.x;
    const int nwg  = gx * gridDim.y;
    const int flat = blockIdx.y * gx + blockIdx.x;
    const int q = nwg >> 3, r = nwg & 7;
    const int xcd = flat & 7, off = flat >> 3;
    const int lid = (xcd < r ? xcd * (q + 1) : r * (q + 1) + (xcd - r) * q) + off;
    const int brow = (lid / gx) * 128;
    const int bcol = (lid % gx) * 128;

    const int wm = (wid >> 1) * 64;
    const int wn = (wid & 1) * 64;

    f32x4 acc[4][4];
    #pragma unroll
    for (int i = 0; i < 4; ++i)
        #pragma unroll
        for (int j = 0; j < 4; ++j)
            #pragma unroll
            for (int rr = 0; rr < 4; ++rr) acc[i][j][rr] = 0.f;

    // prologue: stage tiles 0,1,2 into bufs 0,1,2 (4 vmem ops/wave/tile)
    #pragma unroll
    for (int t = 0; t < 3; ++t) {
        unsigned short* Al = (unsigned short*)(smem + t * 16384);
        unsigned short* Bl = (unsigned short*)(smem + t * 16384 + 8192);
        STAGE_LDS(Al, Ab, brow, t * 32);
        STAGE_LDS(Bl, Bt, bcol, t * 32);
    }

    #pragma unroll
    for (int t = 0; t < NTK; ++t) {
        const int b = t & 3;
        unsigned short* Alc = (unsigned short*)(smem + b * 16384);
        unsigned short* Blc = (unsigned short*)(smem + b * 16384 + 8192);
        // wait for own tile-t loads (t+1,t+2 stay in flight), then rendezvous
        if (t <= NTK - 3) {
            asm volatile("s_waitcnt vmcnt(8)" ::: "memory");
        } else if (t == NTK - 2) {
            asm volatile("s_waitcnt vmcnt(4)" ::: "memory");
        } else {
            asm volatile("s_waitcnt vmcnt(0)" ::: "memory");
        }
        __builtin_amdgcn_s_barrier();
        // stage tile t+3 into buf (t+3)&3 = (t-1)&3: safe, barrier guarantees
        // all waves consumed iter t-1's reads (lgkmcnt before its MFMAs)
        if (t + 3 < NTK) {
            const int bn = (t + 3) & 3;
            unsigned short* Aln = (unsigned short*)(smem + bn * 16384);
            unsigned short* Bln = (unsigned short*)(smem + bn * 16384 + 8192);
            STAGE_LDS(Aln, Ab, brow, (t + 3) * 32);
            STAGE_LDS(Bln, Bt, bcol, (t + 3) * 32);
        }

        bf16x8 af[4], bfr[4];
        #pragma unroll
        for (int mi = 0; mi < 4; ++mi) {
            int row = wm + mi * 16 + (lane & 15);
            af[mi] = *((const bf16x8*)&Alc[row * 32 + (((lane >> 4) ^ ((row >> 1) & 3)) * 8)]);
        }
        #pragma unroll
        for (int nj = 0; nj < 4; ++nj) {
            int row = wn + nj * 16 + (lane & 15);
            bfr[nj] = *((const bf16x8*)&Blc[row * 32 + (((lane >> 4) ^ ((row >> 1) & 3)) * 8)]);
        }
        __builtin_amdgcn_s_setprio(1);
        #pragma unroll
        for (int mi = 0; mi < 4; ++mi)
            #pragma unroll
            for (int nj = 0; nj < 4; ++nj)
                acc[mi][nj] = __builtin_amdgcn_mfma_f32_16x16x32_bf16(
                    af[mi], bfr[nj], acc[mi][nj], 0, 0, 0);
        __builtin_amdgcn_s_setprio(0);
    }
    __builtin_amdgcn_s_barrier();   // protect smem before bounce reuse

    // ---- coalesced epilogue via fp32 LDS bounce (two 64-row halves) ----
    const int ro = tid >> 5;          // 0..7
    const int co = (tid & 31) * 4;    // 0..124
    #pragma unroll
    for (int half = 0; half < 2; ++half) {
        if (wm == half * 64) {
            #pragma unroll
            for (int mi = 0; mi < 4; ++mi)
                #pragma unroll
                for (int nj = 0; nj < 4; ++nj) {
                    int lcol = wn + nj * 16 + (lane & 15);
                    int rb = mi * 16 + ((lane >> 4) << 2);
                    #pragma unroll
                    for (int rr = 0; rr < 4; ++rr)
                        bounce[(rb + rr) * BSTRIDE + lcol] = acc[mi][nj][rr];
                }
        }
        __syncthreads();
        #pragma unroll
        for (int i = 0; i < 8; ++i) {
            int lrow = ro + i * 8;
            int grow = brow + half * 64 + lrow;
            float4 vv = *(const float4*)&bounce[lrow * BSTRIDE + co];
            if (MODE == 0) {
                bf16x4 o;
                o[0] = (short)f2bf(vv.x); o[1] = (short)f2bf(vv.y);
                o[2] = (short)f2bf(vv.z); o[3] = (short)f2bf(vv.w);
                *((bf16x4*)&P[(size_t)grow * NPJ + bcol + co]) = o;
            } else if (grow < NND) {
                int gc = bcol + co;
                if (bcol < 256) {   // uniform: all 4 cols < 300
                    float4 bv = *(const float4*)&bias[gc];
                    bf16x4 old = *(const bf16x4*)&vbf[(size_t)grow * KP + gc];
                    float4 nv;
                    nv.x = bf2f((unsigned short)old[0]) + gelu_exact(vv.x + bv.x);
                    nv.y = bf2f((unsigned short)old[1]) + gelu_exact(vv.y + bv.y);
                    nv.z = bf2f((unsigned short)old[2]) + gelu_exact(vv.z + bv.z);
                    nv.w = bf2f((unsigned short)old[3]) + gelu_exact(vv.w + bv.w);
                    if (last) {
                        *((float4*)&outv[(size_t)grow * DD + gc]) = nv;
                    } else {
                        bf16x4 o;
                        o[0] = (short)f2bf(nv.x); o[1] = (short)f2bf(nv.y);
                        o[2] = (short)f2bf(nv.z); o[3] = (short)f2bf(nv.w);
                        *((bf16x4*)&vbf[(size_t)grow * KP + gc]) = o;
                    }
                } else {
                    #pragma unroll
                    for (int j = 0; j < 4; ++j) {
                        int ccc = gc + j;
                        if (ccc < DD) {
                            float vj = (j == 0) ? vv.x : (j == 1) ? vv.y
                                     : (j == 2) ? vv.z : vv.w;
                            size_t vidx = (size_t)grow * KP + ccc;
                            float nv = bf2f(vbf[vidx]) + gelu_exact(vj + bias[ccc]);
                            if (last) outv[(size_t)grow * DD + ccc] = nv;
                            else      vbf[vidx] = f2bf(nv);
                        }
                    }
                }
            }
        }
        __syncthreads();
    }
}

extern "C" void kernel_launch(void* const* d_in, const int* in_sizes, int n_in,
                              void* d_out, int out_size, void* d_ws, size_t ws_size,
                              hipStream_t stream) {
    const float* x  = (const float*)d_in[0];
    const int*   ei = (const int*)  d_in[1];
    const float* Wr = (const float*)d_in[2];
    const float* br = (const float*)d_in[3];
    const float* Wc = (const float*)d_in[4];
    const float* bc = (const float*)d_in[5];
    const float* Wa = (const float*)d_in[6];
    const float* ba = (const float*)d_in[7];
    float* out = (float*)d_out;

    const size_t P_elems   = (size_t)MPAD * NPJ;   // bf16
    const size_t RC_elems  = (size_t)MPAD * KP;    // bf16
    const size_t V_elems   = (size_t)MPAD * KP;    // bf16
    const size_t Bt_elems  = (size_t)LL * NPJ * KP;
    const size_t Wat_elems = (size_t)NUP * KP;

    unsigned short* P   = (unsigned short*)d_ws;
    unsigned short* RC  = P + P_elems;
    unsigned short* vbf = RC + RC_elems;
    unsigned short* Bt  = vbf + V_elems;
    unsigned short* Wat = Bt + Bt_elems;
    int* deg  = (int*)(Wat + Wat_elems);
    int* off  = deg + 2 * SCN;
    int* curp = off + 2 * SCN;
    int* adj  = curp + 2 * SCN;
    int* bsum = adj + 2 * EE;
    const size_t need = (char*)(bsum + 128) - (char*)d_ws;
    if (ws_size < need) return;  // visible fail (output stays poisoned)

    pack_w<<<2880, 256, 0, stream>>>(Wr, Wc, Wa, Bt, Wat);
    init_vbf<<<(int)((V_elems / 8 + 255) / 256), 256, 0, stream>>>(x, vbf);

    const int* src = ei;
    const int* dst = ei + EE;

    hipMemsetAsync(deg, 0, 2 * SCN * sizeof(int), stream);
    hist_deg<<<(EE + 255) / 256, 256, 0, stream>>>(src, dst, deg);
    scanA<<<dim3(NB, 2), 256, 0, stream>>>(deg, off, bsum);
    scanB<<<1, 256, 0, stream>>>(bsum);
    scanC<<<dim3(NB, 2), 256, 0, stream>>>(off, bsum, curp);
    fill_adj<<<(EE + 255) / 256, 256, 0, stream>>>(src, dst, curp, adj);

    dim3 gproj(NPJ / 128, MPAD / 128);
    dim3 gupd (NUP / 128, MPAD / 128);
    dim3 gagg (MPAD / 4, 2);

    for (int l = 0; l < LL; ++l) {
        gemm_mfma<0><<<gproj, 256, 0, stream>>>(
            vbf, Bt + (size_t)l * NPJ * KP, P, nullptr, nullptr, nullptr, 0);
        aggregate<<<gagg, 256, 0, stream>>>(
            off, adj, P, br + (size_t)l * HH, bc + (size_t)l * HH, RC);
        gemm_mfma<1><<<gupd, 256, 0, stream>>>(
            RC, Wat, nullptr, out, vbf, ba, (l == LL - 1) ? 1 : 0);
    }
}